// Round 2
// baseline (2908.553 us; speedup 1.0000x reference)
//
#include <hip/hip_runtime.h>
#include <hip/hip_bf16.h>

#define B_   128
#define TE_  512
#define TD_  128
#define EH_  512
#define DH_  512
#define KC_  7
#define CC_  105
#define G_   2048   // 4*DH
#define KX_  617    // EH + CC

__device__ __forceinline__ float sigm(float x){ return 1.f/(1.f + __expf(-x)); }

// 512-length fp32 dot, both rows 16B-aligned
__device__ __forceinline__ float dot512f(const float* a, const float* b) {
  const float4* a4 = (const float4*)a; const float4* b4 = (const float4*)b;
  float acc = 0.f;
  #pragma unroll 8
  for (int q = 0; q < 128; ++q) {
    float4 x = a4[q], y = b4[q];
    acc += x.x*y.x + x.y*y.y + x.z*y.z + x.w*y.w;
  }
  return acc;
}

// ---------------- workspace layout (bytes, 256-aligned) ----------------
static const size_t OFF_PHI  = 0;                                        // 512*512 f32
static const size_t OFF_WA   = OFF_PHI  + (size_t)TE_*EH_*4;             // 128*128 f32
static const size_t OFF_HPRE = OFF_WA   + (size_t)B_*TD_*4;              // 128*2048 f32
static const size_t OFF_EP   = OFF_HPRE + (size_t)B_*G_*4;               // 896 f32 (pad)
static const size_t OFF_CP   = OFF_EP   + 4096;                          // 128*105 f32
static const size_t OFF_STAT = ((OFF_CP + (size_t)B_*CC_*4 + 255)/256)*256; // 2*128*128 f32
static const size_t OFF_ET   = ((OFF_STAT + (size_t)2*B_*TD_*4 + 255)/256)*256; // 128*512*128 f32
static const size_t OFF_CI   = OFF_ET   + (size_t)B_*TE_*TD_*4;          // 128*128*512 f32

// ---------------- tiny precompute kernels ----------------
__global__ void k_phi(const float* __restrict__ phi_w, const float* __restrict__ phi_b,
                      float* __restrict__ phi) {
  int e = blockIdx.x * blockDim.x + threadIdx.x;
  if (e >= EH_) return;
  float pb = phi_b[e];
  float acc = 0.f;
  for (int t = 0; t < TE_; ++t) {
    phi[(size_t)t*EH_ + e] = acc + pb;
    acc += phi_w[(size_t)e*TE_ + t];
  }
}

__global__ void k_wa(const float* __restrict__ s_i, const float* __restrict__ Wa_w,
                     const float* __restrict__ Wa_b, const float* __restrict__ va_w,
                     float* __restrict__ wa) {
  int id = blockIdx.x * blockDim.x + threadIdx.x;  // 16384
  int b = id >> 7, d = id & 127;
  float acc = Wa_b[d] + dot512f(s_i + (size_t)b*DH_, Wa_w + (size_t)d*DH_);
  wa[id] = tanhf(acc) * va_w[d];
}

__global__ void k_hpre(const float* __restrict__ s_i, const float* __restrict__ Whh,
                       const float* __restrict__ bih, const float* __restrict__ bhh,
                       float* __restrict__ hpre) {
  int id = blockIdx.x * blockDim.x + threadIdx.x; // 262144
  int b = id >> 11, g = id & 2047;
  hpre[id] = bih[g] + bhh[g] + dot512f(s_i + (size_t)b*DH_, Whh + (size_t)g*DH_);
}

__global__ void k_ep(const float* __restrict__ CNNs, const float* __restrict__ wij_w,
                     const float* __restrict__ wij_b, const float* __restrict__ s_i,
                     float* __restrict__ ep) {
  int id = blockIdx.x * blockDim.x + threadIdx.x;
  if (id >= B_*KC_) return;
  int b = id / KC_, k = id % KC_;
  float acc = wij_b[k];
  const float* cr = CNNs + (size_t)(b*KC_ + k)*CC_;
  const float* wr = wij_w + (size_t)k*KX_;
  for (int c = 0; c < CC_; ++c) acc += cr[c] * wr[c];
  const float* sr = s_i + (size_t)b*DH_;
  const float* wsr = wr + CC_;
  for (int h = 0; h < DH_; ++h) acc += sr[h] * wsr[h];
  ep[id] = tanhf(acc);
}

__global__ void k_cnn_fin(const float* __restrict__ ep, const float* __restrict__ CNNs,
                          float* __restrict__ cp) {
  __shared__ float red[1024];
  __shared__ float apl[B_*KC_];
  int tid = threadIdx.x;
  red[tid] = (tid < B_*KC_) ? ep[tid] : 0.f;
  __syncthreads();
  for (int off = 512; off > 0; off >>= 1) {
    if (tid < off) red[tid] += red[tid + off];
    __syncthreads();
  }
  float S = red[0];
  if (tid < B_*KC_) apl[tid] = __expf(ep[tid]) / S;   // ref: exp(ep)/sum(ep), GLOBAL sum of ep
  __syncthreads();
  for (int idx = tid; idx < B_*CC_; idx += blockDim.x) {
    int b = idx / CC_, c = idx % CC_;
    float acc = 0.f;
    #pragma unroll
    for (int k = 0; k < KC_; ++k)
      acc += apl[b*KC_ + k] * CNNs[(size_t)(b*KC_ + k)*CC_ + c];
    cp[idx] = acc;
  }
}

// ---------------- phase 1: banded attention logits E^T[b,t,i] ----------------
// e[b,i,t] = Cw[b,t,i+512-t]: for t <= i+384 it's tanh(Ua[b,t,s])*va_w[128+s]+vb
// with s=i+384-t; else the t-independent wa term (d = i+512-t in [1,127]).
__global__ void k_band(const float* __restrict__ LSTM, const float* __restrict__ Ua_w,
                       const float* __restrict__ Ua_b, const float* __restrict__ va_w,
                       const float* __restrict__ va_b, const float* __restrict__ phi,
                       const float* __restrict__ wa, float* __restrict__ ET) {
  int t = blockIdx.x, b = blockIdx.y;
  __shared__ alignas(16) float ph[EH_];
  const float* lrow = LSTM + ((size_t)b*TE_ + t)*EH_;
  const float* prow = phi + (size_t)t*EH_;
  for (int e = threadIdx.x; e < EH_; e += blockDim.x)
    ph[e] = lrow[e] * prow[e];
  __syncthreads();
  int i = threadIdx.x;   // 0..127
  float vb = va_b[0];
  float val;
  if (i + 384 >= t) {
    int s = i + 384 - t;                       // 0..511
    float acc = Ua_b[s];
    const float4* ur = (const float4*)(Ua_w + (size_t)s*EH_);
    const float4* p4 = (const float4*)ph;
    #pragma unroll 8
    for (int q = 0; q < EH_/4; ++q) {
      float4 u = ur[q], p = p4[q];
      acc += p.x*u.x + p.y*u.y + p.z*u.z + p.w*u.w;
    }
    val = tanhf(acc) * va_w[TD_ + s] + vb;
  } else {
    val = wa[b*TD_ + (i + TE_ - t)] + vb;      // i+512-t in [1,127]
  }
  ET[((size_t)b*TE_ + t)*TD_ + i] = val;
}

// ---------------- phase 2: softmax stats over t ----------------
__global__ void k_stats(const float* __restrict__ ET, float* __restrict__ stat) {
  int b = blockIdx.x, i = threadIdx.x;        // 128 x 128
  const float* col = ET + (size_t)b*TE_*TD_ + i;
  float m = -1e30f;
  for (int t = 0; t < TE_; ++t) m = fmaxf(m, col[(size_t)t*TD_]);
  float s = 0.f;
  for (int t = 0; t < TE_; ++t) s += __expf(col[(size_t)t*TD_] - m);
  stat[b*TD_ + i] = m;
  stat[(size_t)B_*TD_ + b*TD_ + i] = 1.f/s;
}

// ------ phase 3: c_i[b,i,e] = sum_t softmax(ET)[b,i,t]*LSTM[b,t,e] ------
// ET[b,t,i] is already the A^T layout sA[k][m] wants; softmax applied in staging.
#define P3_BM 64
#define P3_BN 128
#define P3_BK 16
__global__ __launch_bounds__(256) void k_ci(const float* __restrict__ ET,
                                            const float* __restrict__ stat,
                                            const float* __restrict__ LSTM,
                                            float* __restrict__ ci) {
  int b = blockIdx.z;
  int m0 = blockIdx.y * P3_BM;
  int n0 = blockIdx.x * P3_BN;
  __shared__ alignas(16) float sA[P3_BK][P3_BM];
  __shared__ alignas(16) float sB[P3_BK][P3_BN];
  __shared__ float sm[P3_BM], sv[P3_BM];
  int tid = threadIdx.x;
  int tx = tid & 31, ty = tid >> 5;
  if (tid < P3_BM) {
    sm[tid] = stat[b*TD_ + m0 + tid];
    sv[tid] = stat[(size_t)B_*TD_ + b*TD_ + m0 + tid];
  }
  float acc[8][4];
  #pragma unroll
  for (int j = 0; j < 8; ++j)
    #pragma unroll
    for (int l = 0; l < 4; ++l) acc[j][l] = 0.f;

  int krow = tid >> 4;           // 0..15
  int m4   = (tid & 15) * 4;     // 0..60
  int brow = tid >> 4;           // 0..15
  int bnq  = (tid & 15) * 8;     // 0..120
  __syncthreads();               // sm/sv visible

  for (int k0 = 0; k0 < TE_; k0 += P3_BK) {
    float4 ev = *(const float4*)(ET + ((size_t)b*TE_ + k0 + krow)*TD_ + m0 + m4);
    float4 ub0 = *(const float4*)(LSTM + ((size_t)b*TE_ + k0 + brow)*EH_ + n0 + bnq);
    float4 ub1 = *(const float4*)(LSTM + ((size_t)b*TE_ + k0 + brow)*EH_ + n0 + bnq + 4);
    float p0 = __expf(ev.x - sm[m4+0]) * sv[m4+0];
    float p1 = __expf(ev.y - sm[m4+1]) * sv[m4+1];
    float p2 = __expf(ev.z - sm[m4+2]) * sv[m4+2];
    float p3 = __expf(ev.w - sm[m4+3]) * sv[m4+3];
    __syncthreads();
    sA[krow][m4+0] = p0; sA[krow][m4+1] = p1;
    sA[krow][m4+2] = p2; sA[krow][m4+3] = p3;
    *(float4*)&sB[brow][bnq]   = ub0;
    *(float4*)&sB[brow][bnq+4] = ub1;
    __syncthreads();
    #pragma unroll
    for (int k = 0; k < P3_BK; ++k) {
      float4 a0 = *(const float4*)&sA[k][ty*8];
      float4 a1 = *(const float4*)&sA[k][ty*8+4];
      float4 b0 = *(const float4*)&sB[k][tx*4];
      float av[8] = {a0.x,a0.y,a0.z,a0.w,a1.x,a1.y,a1.z,a1.w};
      float bv[4] = {b0.x,b0.y,b0.z,b0.w};
      #pragma unroll
      for (int j = 0; j < 8; ++j)
        #pragma unroll
        for (int l = 0; l < 4; ++l)
          acc[j][l] += av[j]*bv[l];
    }
  }
  #pragma unroll
  for (int j = 0; j < 8; ++j) {
    int mi = m0 + ty*8 + j;
    float4 o; o.x = acc[j][0]; o.y = acc[j][1]; o.z = acc[j][2]; o.w = acc[j][3];
    *(float4*)(ci + ((size_t)b*TD_ + mi)*EH_ + n0 + tx*4) = o;
  }
}

// ------- phase 4: gates GEMM (4 gate planes fused) + LSTM cell epilogue -------
#define P4_BM 64
#define P4_BN 64
#define P4_BK 16
__global__ __launch_bounds__(256) void k_gates(const float* __restrict__ ci,
                                               const float* __restrict__ cp,
                                               const float* __restrict__ Wih,
                                               const float* __restrict__ hpre,
                                               const float* __restrict__ m_i,
                                               float* __restrict__ out) {
  int n0 = blockIdx.x * P4_BN;    // dh tile (512/64 = 8)
  int m0 = blockIdx.y * P4_BM;    // mi tile (16384/64 = 256)
  int tid = threadIdx.x;
  int tx = tid & 31, ty = tid >> 5;
  __shared__ alignas(16) float sA[P4_BK][P4_BM];
  __shared__ alignas(16) float sB[4][P4_BK][P4_BN];
  float acc[4][8][2];
  #pragma unroll
  for (int g = 0; g < 4; ++g)
    #pragma unroll
    for (int j = 0; j < 8; ++j) { acc[g][j][0] = 0.f; acc[g][j][1] = 0.f; }

  int arow = tid >> 2, akq = (tid & 3) * 4;  // A: 64 rows x 4 k each
  int bg = tid >> 6, bn = tid & 63;          // B: 4 gates x 64 rows x 16 k

  for (int k0 = 0; k0 < 624; k0 += P4_BK) {  // 39 tiles cover K=617
    float av[4];
    int mi = m0 + arow; int bb = mi >> 7;
    if (k0 < EH_) {
      float4 v = *(const float4*)(ci + (size_t)mi*EH_ + k0 + akq);
      av[0] = v.x; av[1] = v.y; av[2] = v.z; av[3] = v.w;
    } else {
      #pragma unroll
      for (int j = 0; j < 4; ++j) {
        int k = k0 + akq + j;
        av[j] = (k < KX_) ? cp[bb*CC_ + (k - EH_)] : 0.f;
      }
    }
    float bv[P4_BK];
    const float* wrow = Wih + (size_t)(bg*DH_ + n0 + bn)*KX_ + k0;
    #pragma unroll
    for (int j = 0; j < P4_BK; ++j) {
      int k = k0 + j;
      bv[j] = (k < KX_) ? wrow[j] : 0.f;
    }
    __syncthreads();
    #pragma unroll
    for (int j = 0; j < 4; ++j) sA[akq+j][arow] = av[j];
    #pragma unroll
    for (int j = 0; j < P4_BK; ++j) sB[bg][j][bn] = bv[j];
    __syncthreads();
    #pragma unroll
    for (int k = 0; k < P4_BK; ++k) {
      float4 a0 = *(const float4*)&sA[k][ty*8];
      float4 a1 = *(const float4*)&sA[k][ty*8+4];
      float av8[8] = {a0.x,a0.y,a0.z,a0.w,a1.x,a1.y,a1.z,a1.w};
      #pragma unroll
      for (int g = 0; g < 4; ++g) {
        float2 bg2 = *(const float2*)&sB[g][k][tx*2];
        #pragma unroll
        for (int j = 0; j < 8; ++j) {
          acc[g][j][0] += av8[j]*bg2.x;
          acc[g][j][1] += av8[j]*bg2.y;
        }
      }
    }
  }
  #pragma unroll
  for (int j = 0; j < 8; ++j) {
    int mi = m0 + ty*8 + j;
    int bb = mi >> 7;
    const float* hp = hpre + (size_t)bb*G_;
    #pragma unroll
    for (int l = 0; l < 2; ++l) {
      int dh = n0 + tx*2 + l;
      float ig = acc[0][j][l] + hp[dh];
      float fg = acc[1][j][l] + hp[512 + dh];
      float gg = acc[2][j][l] + hp[1024 + dh];
      float og = acc[3][j][l] + hp[1536 + dh];
      float c  = sigm(fg)*m_i[(size_t)bb*DH_ + dh] + sigm(ig)*tanhf(gg);
      float h  = sigm(og)*tanhf(c);
      out[(size_t)mi*DH_ + dh] = h;
    }
  }
}

extern "C" void kernel_launch(void* const* d_in, const int* in_sizes, int n_in,
                              void* d_out, int out_size, void* d_ws, size_t ws_size,
                              hipStream_t stream) {
  (void)in_sizes; (void)n_in; (void)out_size; (void)ws_size;
  const float* LSTM  = (const float*)d_in[0];
  const float* CNNs  = (const float*)d_in[1];
  const float* Wa_w  = (const float*)d_in[2];
  const float* Wa_b  = (const float*)d_in[3];
  const float* Ua_w  = (const float*)d_in[4];
  const float* Ua_b  = (const float*)d_in[5];
  const float* va_w  = (const float*)d_in[6];
  const float* va_b  = (const float*)d_in[7];
  const float* phi_w = (const float*)d_in[8];
  const float* phi_b = (const float*)d_in[9];
  const float* Wih   = (const float*)d_in[10];
  const float* Whh   = (const float*)d_in[11];
  const float* bih   = (const float*)d_in[12];
  const float* bhh   = (const float*)d_in[13];
  const float* wij_w = (const float*)d_in[14];
  const float* wij_b = (const float*)d_in[15];
  const float* s_i   = (const float*)d_in[16];
  const float* m_i   = (const float*)d_in[17];
  float* out = (float*)d_out;
  char* ws = (char*)d_ws;

  float* phi  = (float*)(ws + OFF_PHI);
  float* wa   = (float*)(ws + OFF_WA);
  float* hpre = (float*)(ws + OFF_HPRE);
  float* ep   = (float*)(ws + OFF_EP);
  float* cp   = (float*)(ws + OFF_CP);
  float* stat = (float*)(ws + OFF_STAT);
  float* ET   = (float*)(ws + OFF_ET);
  float* ci   = (float*)(ws + OFF_CI);

  k_phi    <<<dim3(2),        dim3(256),  0, stream>>>(phi_w, phi_b, phi);
  k_wa     <<<dim3(64),       dim3(256),  0, stream>>>(s_i, Wa_w, Wa_b, va_w, wa);
  k_hpre   <<<dim3(1024),     dim3(256),  0, stream>>>(s_i, Whh, bih, bhh, hpre);
  k_ep     <<<dim3(4),        dim3(256),  0, stream>>>(CNNs, wij_w, wij_b, s_i, ep);
  k_cnn_fin<<<dim3(1),        dim3(1024), 0, stream>>>(ep, CNNs, cp);
  k_band   <<<dim3(512,128),  dim3(128),  0, stream>>>(LSTM, Ua_w, Ua_b, va_w, va_b, phi, wa, ET);
  k_stats  <<<dim3(128),      dim3(128),  0, stream>>>(ET, stat);
  k_ci     <<<dim3(4,2,128),  dim3(256),  0, stream>>>(ET, stat, LSTM, ci);
  k_gates  <<<dim3(8,256),    dim3(256),  0, stream>>>(ci, cp, Wih, hpre, m_i, out);
}

// Round 3
// 1292.268 us; speedup vs baseline: 2.2507x; 2.2507x over previous
//
#include <hip/hip_runtime.h>
#include <hip/hip_bf16.h>

#define B_   128
#define TE_  512
#define TD_  128
#define EH_  512
#define DH_  512
#define KC_  7
#define CC_  105
#define G_   2048   // 4*DH
#define KX_  617    // EH + CC

typedef __attribute__((ext_vector_type(8))) short bf16x8;
typedef __attribute__((ext_vector_type(4))) float f32x4;

__device__ __forceinline__ float sigm(float x){ return 1.f/(1.f + __expf(-x)); }

// fp32 -> bf16 (RNE), bit-level (no header API dependence)
__device__ __forceinline__ unsigned short f2bf(float f){
  unsigned int u = __float_as_uint(f);
  unsigned int r = (u + 0x7fffu + ((u >> 16) & 1u)) >> 16;
  return (unsigned short)r;
}

// 512-length fp32 dot, both rows 16B-aligned
__device__ __forceinline__ float dot512f(const float* a, const float* b) {
  const float4* a4 = (const float4*)a; const float4* b4 = (const float4*)b;
  float acc = 0.f;
  #pragma unroll 8
  for (int q = 0; q < 128; ++q) {
    float4 x = a4[q], y = b4[q];
    acc += x.x*y.x + x.y*y.y + x.z*y.z + x.w*y.w;
  }
  return acc;
}

// ---------------- workspace layout (bytes, 256-aligned) ----------------
static const size_t OFF_PHI  = 0;                                        // 512*512 f32
static const size_t OFF_WA   = OFF_PHI  + (size_t)TE_*EH_*4;             // 128*128 f32
static const size_t OFF_HPRE = OFF_WA   + (size_t)B_*TD_*4;              // 128*2048 f32
static const size_t OFF_EP   = OFF_HPRE + (size_t)B_*G_*4;               // 896 f32 (pad)
static const size_t OFF_CP   = OFF_EP   + 4096;                          // 128*105 f32
static const size_t OFF_STAT = ((OFF_CP + (size_t)B_*CC_*4 + 255)/256)*256; // 2*128*128 f32
static const size_t OFF_ET   = ((OFF_STAT + (size_t)2*B_*TD_*4 + 255)/256)*256; // 128*512*128 f32
static const size_t OFF_CI   = OFF_ET   + (size_t)B_*TE_*TD_*4;          // 128*128*512 f32

// ---------------- tiny precompute kernels ----------------
__global__ void k_phi(const float* __restrict__ phi_w, const float* __restrict__ phi_b,
                      float* __restrict__ phi) {
  int e = blockIdx.x * blockDim.x + threadIdx.x;
  if (e >= EH_) return;
  float pb = phi_b[e];
  float acc = 0.f;
  for (int t = 0; t < TE_; ++t) {
    phi[(size_t)t*EH_ + e] = acc + pb;
    acc += phi_w[(size_t)e*TE_ + t];
  }
}

__global__ void k_wa(const float* __restrict__ s_i, const float* __restrict__ Wa_w,
                     const float* __restrict__ Wa_b, const float* __restrict__ va_w,
                     float* __restrict__ wa) {
  int id = blockIdx.x * blockDim.x + threadIdx.x;  // 16384
  int b = id >> 7, d = id & 127;
  float acc = Wa_b[d] + dot512f(s_i + (size_t)b*DH_, Wa_w + (size_t)d*DH_);
  wa[id] = tanhf(acc) * va_w[d];
}

__global__ void k_hpre(const float* __restrict__ s_i, const float* __restrict__ Whh,
                       const float* __restrict__ bih, const float* __restrict__ bhh,
                       float* __restrict__ hpre) {
  int id = blockIdx.x * blockDim.x + threadIdx.x; // 262144
  int b = id >> 11, g = id & 2047;
  hpre[id] = bih[g] + bhh[g] + dot512f(s_i + (size_t)b*DH_, Whh + (size_t)g*DH_);
}

__global__ void k_ep(const float* __restrict__ CNNs, const float* __restrict__ wij_w,
                     const float* __restrict__ wij_b, const float* __restrict__ s_i,
                     float* __restrict__ ep) {
  int id = blockIdx.x * blockDim.x + threadIdx.x;
  if (id >= B_*KC_) return;
  int b = id / KC_, k = id % KC_;
  float acc = wij_b[k];
  const float* cr = CNNs + (size_t)(b*KC_ + k)*CC_;
  const float* wr = wij_w + (size_t)k*KX_;
  for (int c = 0; c < CC_; ++c) acc += cr[c] * wr[c];
  const float* sr = s_i + (size_t)b*DH_;
  const float* wsr = wr + CC_;
  for (int h = 0; h < DH_; ++h) acc += sr[h] * wsr[h];
  ep[id] = tanhf(acc);
}

__global__ void k_cnn_fin(const float* __restrict__ ep, const float* __restrict__ CNNs,
                          float* __restrict__ cp) {
  __shared__ float red[1024];
  __shared__ float apl[B_*KC_];
  int tid = threadIdx.x;
  red[tid] = (tid < B_*KC_) ? ep[tid] : 0.f;
  __syncthreads();
  for (int off = 512; off > 0; off >>= 1) {
    if (tid < off) red[tid] += red[tid + off];
    __syncthreads();
  }
  float S = red[0];
  if (tid < B_*KC_) apl[tid] = __expf(ep[tid]) / S;   // ref: exp(ep)/sum(ep), GLOBAL sum of ep
  __syncthreads();
  for (int idx = tid; idx < B_*CC_; idx += blockDim.x) {
    int b = idx / CC_, c = idx % CC_;
    float acc = 0.f;
    #pragma unroll
    for (int k = 0; k < KC_; ++k)
      acc += apl[b*KC_ + k] * CNNs[(size_t)(b*KC_ + k)*CC_ + c];
    cp[idx] = acc;
  }
}

// ---------- phase 1: banded logits as MFMA bf16 band-GEMM ----------
// acc[t,s] = sum_e (LSTM[b,t,e]*phi[t,e]) * Ua_w[s,e]; s = i+384-t.
// Per (b, 64-row t-tile): s-stripe = [321-t0, 511-t0] (width 191, pad N=192).
// Epilogue: i = s+t-384 in [0,128) -> ET[b,t,i] = tanh(acc)*va_w[128+s]+vb,
// or (s<0) the t-independent wa path.
#define BMM_M 64
#define BMM_N 192
#define LDA_  40   // shorts per row: 32 data + 8 pad (80B stride, banks spread)
#define LDB_  40
__global__ __launch_bounds__(256) void k_bandmm(const float* __restrict__ LSTM,
                                                const float* __restrict__ phi,
                                                const float* __restrict__ Ua_w,
                                                const float* __restrict__ Ua_b,
                                                const float* __restrict__ va_w,
                                                const float* __restrict__ va_b,
                                                const float* __restrict__ wa,
                                                float* __restrict__ ET) {
  int t0 = blockIdx.x * BMM_M;   // 8 tiles
  int b  = blockIdx.y;           // 128
  int s_base = 321 - t0;
  __shared__ short sA[BMM_M * LDA_];
  __shared__ short sB[BMM_N * LDB_];
  int tid = threadIdx.x;
  int wave = tid >> 6, lane = tid & 63;
  int quad = lane >> 4, l16 = lane & 15;

  f32x4 acc[4][3];
  #pragma unroll
  for (int m = 0; m < 4; ++m)
    #pragma unroll
    for (int n = 0; n < 3; ++n)
      acc[m][n] = (f32x4){0.f, 0.f, 0.f, 0.f};

  // staging assignments (constant over K-loop)
  int arow = tid >> 2;             // 0..63
  int ach  = (tid & 3) * 8;        // 0,8,16,24 (shorts)

  for (int k0 = 0; k0 < EH_; k0 += 32) {
    // ---- A: ph[t0+arow][k0+ach..+7] = LSTM*phi, fp32->bf16 ----
    const float4* lp = (const float4*)(LSTM + ((size_t)b*TE_ + t0 + arow)*EH_ + k0 + ach);
    const float4* pp = (const float4*)(phi + (size_t)(t0 + arow)*EH_ + k0 + ach);
    float4 l0 = lp[0], l1 = lp[1], p0 = pp[0], p1 = pp[1];
    unsigned short at[8];
    at[0]=f2bf(l0.x*p0.x); at[1]=f2bf(l0.y*p0.y); at[2]=f2bf(l0.z*p0.z); at[3]=f2bf(l0.w*p0.w);
    at[4]=f2bf(l1.x*p1.x); at[5]=f2bf(l1.y*p1.y); at[6]=f2bf(l1.z*p1.z); at[7]=f2bf(l1.w*p1.w);
    // ---- B: Ua_w[s_base+row][k0+ch..+7] fp32->bf16, 3 chunks/thread ----
    unsigned short bt[3][8];
    int brow[3];
    #pragma unroll
    for (int c = 0; c < 3; ++c) {
      int idx = c*256 + tid;
      brow[c] = idx >> 2;
      int ch = (idx & 3) * 8;
      int s = s_base + brow[c];
      int sc = s < 0 ? 0 : (s > 511 ? 511 : s);
      const float4* up = (const float4*)(Ua_w + (size_t)sc*EH_ + k0 + ch);
      float4 u0 = up[0], u1 = up[1];
      bt[c][0]=f2bf(u0.x); bt[c][1]=f2bf(u0.y); bt[c][2]=f2bf(u0.z); bt[c][3]=f2bf(u0.w);
      bt[c][4]=f2bf(u1.x); bt[c][5]=f2bf(u1.y); bt[c][6]=f2bf(u1.z); bt[c][7]=f2bf(u1.w);
    }
    __syncthreads();   // previous iteration's reads done
    *(uint4*)&sA[arow*LDA_ + ach] = *(uint4*)at;
    #pragma unroll
    for (int c = 0; c < 3; ++c) {
      int idx = c*256 + tid;
      int ch = (idx & 3) * 8;
      *(uint4*)&sB[brow[c]*LDB_ + ch] = *(uint4*)bt[c];
    }
    __syncthreads();
    // ---- MFMA: wave w owns N cols [w*48, w*48+47] ----
    bf16x8 bf[3];
    #pragma unroll
    for (int n = 0; n < 3; ++n)
      bf[n] = *(const bf16x8*)&sB[(l16 + (wave*3 + n)*16)*LDB_ + quad*8];
    #pragma unroll
    for (int m = 0; m < 4; ++m) {
      bf16x8 af = *(const bf16x8*)&sA[(l16 + m*16)*LDA_ + quad*8];
      #pragma unroll
      for (int n = 0; n < 3; ++n)
        acc[m][n] = __builtin_amdgcn_mfma_f32_16x16x32_bf16(af, bf[n], acc[m][n], 0, 0, 0);
    }
  }

  // ---- epilogue: map (t,s) -> (t,i), tanh*va_w+vb or wa path ----
  float vb = va_b[0];
  #pragma unroll
  for (int n = 0; n < 3; ++n) {
    int s = s_base + wave*48 + n*16 + l16;
    #pragma unroll
    for (int m = 0; m < 4; ++m) {
      #pragma unroll
      for (int r = 0; r < 4; ++r) {
        int t = t0 + m*16 + quad*4 + r;
        int i = s + t - 384;
        if (i >= 0 && i < TD_) {
          float val;
          if (s >= 0) val = tanhf(acc[m][n][r] + Ua_b[s]) * va_w[TD_ + s] + vb;
          else        val = wa[b*TD_ + s + 128] + vb;
          ET[((size_t)b*TE_ + t)*TD_ + i] = val;
        }
      }
    }
  }
}

// ---------------- phase 2: softmax stats over t ----------------
__global__ void k_stats(const float* __restrict__ ET, float* __restrict__ stat) {
  int b = blockIdx.x, i = threadIdx.x;        // 128 x 128
  const float* col = ET + (size_t)b*TE_*TD_ + i;
  float m = -1e30f;
  for (int t = 0; t < TE_; ++t) m = fmaxf(m, col[(size_t)t*TD_]);
  float s = 0.f;
  for (int t = 0; t < TE_; ++t) s += __expf(col[(size_t)t*TD_] - m);
  stat[b*TD_ + i] = m;
  stat[(size_t)B_*TD_ + b*TD_ + i] = 1.f/s;
}

// ------ phase 3: c_i[b,i,e] = sum_t softmax(ET)[b,i,t]*LSTM[b,t,e] ------
#define P3_BM 64
#define P3_BN 128
#define P3_BK 16
__global__ __launch_bounds__(256) void k_ci(const float* __restrict__ ET,
                                            const float* __restrict__ stat,
                                            const float* __restrict__ LSTM,
                                            float* __restrict__ ci) {
  int b = blockIdx.z;
  int m0 = blockIdx.y * P3_BM;
  int n0 = blockIdx.x * P3_BN;
  __shared__ alignas(16) float sA[P3_BK][P3_BM];
  __shared__ alignas(16) float sB[P3_BK][P3_BN];
  __shared__ float sm[P3_BM], sv[P3_BM];
  int tid = threadIdx.x;
  int tx = tid & 31, ty = tid >> 5;
  if (tid < P3_BM) {
    sm[tid] = stat[b*TD_ + m0 + tid];
    sv[tid] = stat[(size_t)B_*TD_ + b*TD_ + m0 + tid];
  }
  float acc[8][4];
  #pragma unroll
  for (int j = 0; j < 8; ++j)
    #pragma unroll
    for (int l = 0; l < 4; ++l) acc[j][l] = 0.f;

  int krow = tid >> 4;           // 0..15
  int m4   = (tid & 15) * 4;     // 0..60
  int brow = tid >> 4;           // 0..15
  int bnq  = (tid & 15) * 8;     // 0..120
  __syncthreads();               // sm/sv visible

  for (int k0 = 0; k0 < TE_; k0 += P3_BK) {
    float4 ev = *(const float4*)(ET + ((size_t)b*TE_ + k0 + krow)*TD_ + m0 + m4);
    float4 ub0 = *(const float4*)(LSTM + ((size_t)b*TE_ + k0 + brow)*EH_ + n0 + bnq);
    float4 ub1 = *(const float4*)(LSTM + ((size_t)b*TE_ + k0 + brow)*EH_ + n0 + bnq + 4);
    float p0 = __expf(ev.x - sm[m4+0]) * sv[m4+0];
    float p1 = __expf(ev.y - sm[m4+1]) * sv[m4+1];
    float p2 = __expf(ev.z - sm[m4+2]) * sv[m4+2];
    float p3 = __expf(ev.w - sm[m4+3]) * sv[m4+3];
    __syncthreads();
    sA[krow][m4+0] = p0; sA[krow][m4+1] = p1;
    sA[krow][m4+2] = p2; sA[krow][m4+3] = p3;
    *(float4*)&sB[brow][bnq]   = ub0;
    *(float4*)&sB[brow][bnq+4] = ub1;
    __syncthreads();
    #pragma unroll
    for (int k = 0; k < P3_BK; ++k) {
      float4 a0 = *(const float4*)&sA[k][ty*8];
      float4 a1 = *(const float4*)&sA[k][ty*8+4];
      float4 b0 = *(const float4*)&sB[k][tx*4];
      float av[8] = {a0.x,a0.y,a0.z,a0.w,a1.x,a1.y,a1.z,a1.w};
      float bv[4] = {b0.x,b0.y,b0.z,b0.w};
      #pragma unroll
      for (int j = 0; j < 8; ++j)
        #pragma unroll
        for (int l = 0; l < 4; ++l)
          acc[j][l] += av[j]*bv[l];
    }
  }
  #pragma unroll
  for (int j = 0; j < 8; ++j) {
    int mi = m0 + ty*8 + j;
    float4 o; o.x = acc[j][0]; o.y = acc[j][1]; o.z = acc[j][2]; o.w = acc[j][3];
    *(float4*)(ci + ((size_t)b*TD_ + mi)*EH_ + n0 + tx*4) = o;
  }
}

// ------- phase 4: gates GEMM (4 gate planes fused) + LSTM cell epilogue -------
#define P4_BM 64
#define P4_BN 64
#define P4_BK 16
__global__ __launch_bounds__(256) void k_gates(const float* __restrict__ ci,
                                               const float* __restrict__ cp,
                                               const float* __restrict__ Wih,
                                               const float* __restrict__ hpre,
                                               const float* __restrict__ m_i,
                                               float* __restrict__ out) {
  int n0 = blockIdx.x * P4_BN;    // dh tile (512/64 = 8)
  int m0 = blockIdx.y * P4_BM;    // mi tile (16384/64 = 256)
  int tid = threadIdx.x;
  int tx = tid & 31, ty = tid >> 5;
  __shared__ alignas(16) float sA[P4_BK][P4_BM];
  __shared__ alignas(16) float sB[4][P4_BK][P4_BN];
  float acc[4][8][2];
  #pragma unroll
  for (int g = 0; g < 4; ++g)
    #pragma unroll
    for (int j = 0; j < 8; ++j) { acc[g][j][0] = 0.f; acc[g][j][1] = 0.f; }

  int arow = tid >> 2, akq = (tid & 3) * 4;  // A: 64 rows x 4 k each
  int bg = tid >> 6, bn = tid & 63;          // B: 4 gates x 64 rows x 16 k

  for (int k0 = 0; k0 < 624; k0 += P4_BK) {  // 39 tiles cover K=617
    float av[4];
    int mi = m0 + arow; int bb = mi >> 7;
    if (k0 < EH_) {
      float4 v = *(const float4*)(ci + (size_t)mi*EH_ + k0 + akq);
      av[0] = v.x; av[1] = v.y; av[2] = v.z; av[3] = v.w;
    } else {
      #pragma unroll
      for (int j = 0; j < 4; ++j) {
        int k = k0 + akq + j;
        av[j] = (k < KX_) ? cp[bb*CC_ + (k - EH_)] : 0.f;
      }
    }
    float bv[P4_BK];
    const float* wrow = Wih + (size_t)(bg*DH_ + n0 + bn)*KX_ + k0;
    #pragma unroll
    for (int j = 0; j < P4_BK; ++j) {
      int k = k0 + j;
      bv[j] = (k < KX_) ? wrow[j] : 0.f;
    }
    __syncthreads();
    #pragma unroll
    for (int j = 0; j < 4; ++j) sA[akq+j][arow] = av[j];
    #pragma unroll
    for (int j = 0; j < P4_BK; ++j) sB[bg][j][bn] = bv[j];
    __syncthreads();
    #pragma unroll
    for (int k = 0; k < P4_BK; ++k) {
      float4 a0 = *(const float4*)&sA[k][ty*8];
      float4 a1 = *(const float4*)&sA[k][ty*8+4];
      float av8[8] = {a0.x,a0.y,a0.z,a0.w,a1.x,a1.y,a1.z,a1.w};
      #pragma unroll
      for (int g = 0; g < 4; ++g) {
        float2 bg2 = *(const float2*)&sB[g][k][tx*2];
        #pragma unroll
        for (int j = 0; j < 8; ++j) {
          acc[g][j][0] += av8[j]*bg2.x;
          acc[g][j][1] += av8[j]*bg2.y;
        }
      }
    }
  }
  #pragma unroll
  for (int j = 0; j < 8; ++j) {
    int mi = m0 + ty*8 + j;
    int bb = mi >> 7;
    const float* hp = hpre + (size_t)bb*G_;
    #pragma unroll
    for (int l = 0; l < 2; ++l) {
      int dh = n0 + tx*2 + l;
      float ig = acc[0][j][l] + hp[dh];
      float fg = acc[1][j][l] + hp[512 + dh];
      float gg = acc[2][j][l] + hp[1024 + dh];
      float og = acc[3][j][l] + hp[1536 + dh];
      float c  = sigm(fg)*m_i[(size_t)bb*DH_ + dh] + sigm(ig)*tanhf(gg);
      float h  = sigm(og)*tanhf(c);
      out[(size_t)mi*DH_ + dh] = h;
    }
  }
}

extern "C" void kernel_launch(void* const* d_in, const int* in_sizes, int n_in,
                              void* d_out, int out_size, void* d_ws, size_t ws_size,
                              hipStream_t stream) {
  (void)in_sizes; (void)n_in; (void)out_size; (void)ws_size;
  const float* LSTM  = (const float*)d_in[0];
  const float* CNNs  = (const float*)d_in[1];
  const float* Wa_w  = (const float*)d_in[2];
  const float* Wa_b  = (const float*)d_in[3];
  const float* Ua_w  = (const float*)d_in[4];
  const float* Ua_b  = (const float*)d_in[5];
  const float* va_w  = (const float*)d_in[6];
  const float* va_b  = (const float*)d_in[7];
  const float* phi_w = (const float*)d_in[8];
  const float* phi_b = (const float*)d_in[9];
  const float* Wih   = (const float*)d_in[10];
  const float* Whh   = (const float*)d_in[11];
  const float* bih   = (const float*)d_in[12];
  const float* bhh   = (const float*)d_in[13];
  const float* wij_w = (const float*)d_in[14];
  const float* wij_b = (const float*)d_in[15];
  const float* s_i   = (const float*)d_in[16];
  const float* m_i   = (const float*)d_in[17];
  float* out = (float*)d_out;
  char* ws = (char*)d_ws;

  float* phi  = (float*)(ws + OFF_PHI);
  float* wa   = (float*)(ws + OFF_WA);
  float* hpre = (float*)(ws + OFF_HPRE);
  float* ep   = (float*)(ws + OFF_EP);
  float* cp   = (float*)(ws + OFF_CP);
  float* stat = (float*)(ws + OFF_STAT);
  float* ET   = (float*)(ws + OFF_ET);
  float* ci   = (float*)(ws + OFF_CI);

  k_phi    <<<dim3(2),        dim3(256),  0, stream>>>(phi_w, phi_b, phi);
  k_wa     <<<dim3(64),       dim3(256),  0, stream>>>(s_i, Wa_w, Wa_b, va_w, wa);
  k_hpre   <<<dim3(1024),     dim3(256),  0, stream>>>(s_i, Whh, bih, bhh, hpre);
  k_ep     <<<dim3(4),        dim3(256),  0, stream>>>(CNNs, wij_w, wij_b, s_i, ep);
  k_cnn_fin<<<dim3(1),        dim3(1024), 0, stream>>>(ep, CNNs, cp);
  k_bandmm <<<dim3(8,128),    dim3(256),  0, stream>>>(LSTM, phi, Ua_w, Ua_b, va_w, va_b, wa, ET);
  k_stats  <<<dim3(128),      dim3(128),  0, stream>>>(ET, stat);
  k_ci     <<<dim3(4,2,128),  dim3(256),  0, stream>>>(ET, stat, LSTM, ci);
  k_gates  <<<dim3(8,256),    dim3(256),  0, stream>>>(ci, cp, Wih, hpre, m_i, out);
}

// Round 4
// 620.690 us; speedup vs baseline: 4.6860x; 2.0820x over previous
//
#include <hip/hip_runtime.h>
#include <hip/hip_bf16.h>

#define B_   128
#define TE_  512
#define TD_  128
#define EH_  512
#define DH_  512
#define KC_  7
#define CC_  105
#define G_   2048   // 4*DH
#define KX_  617    // EH + CC
#define KP_  640    // padded K for gates GEMM

typedef __attribute__((ext_vector_type(8))) short bf16x8;
typedef __attribute__((ext_vector_type(4))) float f32x4;

__device__ __forceinline__ float sigm(float x){ return 1.f/(1.f + __expf(-x)); }

// fp32 -> bf16 (RNE), bit-level
__device__ __forceinline__ unsigned short f2bf(float f){
  unsigned int u = __float_as_uint(f);
  unsigned int r = (u + 0x7fffu + ((u >> 16) & 1u)) >> 16;
  return (unsigned short)r;
}

__device__ __forceinline__ float dot512f(const float* a, const float* b) {
  const float4* a4 = (const float4*)a; const float4* b4 = (const float4*)b;
  float acc = 0.f;
  #pragma unroll 8
  for (int q = 0; q < 128; ++q) {
    float4 x = a4[q], y = b4[q];
    acc += x.x*y.x + x.y*y.y + x.z*y.z + x.w*y.w;
  }
  return acc;
}

// ---------------- workspace layout (bytes) ----------------
static const size_t OFF_PHI  = 0;                                         // 1 MB
static const size_t OFF_WA   = OFF_PHI  + (size_t)TE_*EH_*4;              // 64 KB
static const size_t OFF_HPRE = OFF_WA   + (size_t)B_*TD_*4;               // 1 MB
static const size_t OFF_EP   = OFF_HPRE + (size_t)B_*G_*4;                // 4 KB
static const size_t OFF_CP   = OFF_EP   + 4096;                           // 53.8 KB
static const size_t OFF_STAT = ((OFF_CP + (size_t)B_*CC_*4 + 255)/256)*256; // 128 KB
static const size_t OFF_ET   = ((OFF_STAT + (size_t)2*B_*TD_*4 + 255)/256)*256; // 32 MB (X bf16 aliases, 21 MB)
static const size_t OFF_P    = OFF_ET + (size_t)B_*TE_*TD_*4;             // 16 MB bf16
static const size_t OFF_LT   = OFF_P  + (size_t)B_*TD_*TE_*2;             // 67 MB bf16
static const size_t OFF_WR   = OFF_LT + (size_t)B_*TE_*EH_*2;             // 2.6 MB bf16
// end = OFF_WR + 2048*640*2  ~= 117 MB  (<= 133 MB proven available in R2/R3)

// ---------------- tiny precompute kernels ----------------
__global__ void k_phi(const float* __restrict__ phi_w, const float* __restrict__ phi_b,
                      float* __restrict__ phi) {
  int e = blockIdx.x * blockDim.x + threadIdx.x;
  if (e >= EH_) return;
  float pb = phi_b[e];
  float acc = 0.f;
  for (int t = 0; t < TE_; ++t) {
    phi[(size_t)t*EH_ + e] = acc + pb;
    acc += phi_w[(size_t)e*TE_ + t];
  }
}

__global__ void k_wa(const float* __restrict__ s_i, const float* __restrict__ Wa_w,
                     const float* __restrict__ Wa_b, const float* __restrict__ va_w,
                     float* __restrict__ wa) {
  int id = blockIdx.x * blockDim.x + threadIdx.x;  // 16384
  int b = id >> 7, d = id & 127;
  float acc = Wa_b[d] + dot512f(s_i + (size_t)b*DH_, Wa_w + (size_t)d*DH_);
  wa[id] = tanhf(acc) * va_w[d];
}

__global__ void k_hpre(const float* __restrict__ s_i, const float* __restrict__ Whh,
                       const float* __restrict__ bih, const float* __restrict__ bhh,
                       float* __restrict__ hpre) {
  int id = blockIdx.x * blockDim.x + threadIdx.x; // 262144
  int b = id >> 11, g = id & 2047;
  hpre[id] = bih[g] + bhh[g] + dot512f(s_i + (size_t)b*DH_, Whh + (size_t)g*DH_);
}

__global__ void k_ep(const float* __restrict__ CNNs, const float* __restrict__ wij_w,
                     const float* __restrict__ wij_b, const float* __restrict__ s_i,
                     float* __restrict__ ep) {
  int id = blockIdx.x * blockDim.x + threadIdx.x;
  if (id >= B_*KC_) return;
  int b = id / KC_, k = id % KC_;
  float acc = wij_b[k];
  const float* cr = CNNs + (size_t)(b*KC_ + k)*CC_;
  const float* wr = wij_w + (size_t)k*KX_;
  for (int c = 0; c < CC_; ++c) acc += cr[c] * wr[c];
  const float* sr = s_i + (size_t)b*DH_;
  const float* wsr = wr + CC_;
  for (int h = 0; h < DH_; ++h) acc += sr[h] * wsr[h];
  ep[id] = tanhf(acc);
}

__global__ void k_cnn_fin(const float* __restrict__ ep, const float* __restrict__ CNNs,
                          float* __restrict__ cp) {
  __shared__ float red[1024];
  __shared__ float apl[B_*KC_];
  int tid = threadIdx.x;
  red[tid] = (tid < B_*KC_) ? ep[tid] : 0.f;
  __syncthreads();
  for (int off = 512; off > 0; off >>= 1) {
    if (tid < off) red[tid] += red[tid + off];
    __syncthreads();
  }
  float S = red[0];
  if (tid < B_*KC_) apl[tid] = __expf(ep[tid]) / S;   // ref: exp(ep)/sum(ep), GLOBAL sum
  __syncthreads();
  for (int idx = tid; idx < B_*CC_; idx += blockDim.x) {
    int b = idx / CC_, c = idx % CC_;
    float acc = 0.f;
    #pragma unroll
    for (int k = 0; k < KC_; ++k)
      acc += apl[b*KC_ + k] * CNNs[(size_t)(b*KC_ + k)*CC_ + c];
    cp[idx] = acc;
  }
}

// ---- Wih fp32 [2048][617] -> bf16 [2048][640], rows reordered nr = dh*4+gate ----
__global__ void k_cvtW(const float* __restrict__ Wih, unsigned short* __restrict__ Wr) {
  int id = blockIdx.x * 256 + threadIdx.x;    // 2048*80
  int nr = id / 80, c8 = (id % 80) * 8;
  int gate = nr & 3, dh = nr >> 2;
  const float* src = Wih + (size_t)(gate*DH_ + dh)*KX_;
  unsigned short o[8];
  #pragma unroll
  for (int j = 0; j < 8; ++j) {
    int col = c8 + j;
    o[j] = (col < KX_) ? f2bf(src[col]) : 0;
  }
  *(uint4*)(Wr + (size_t)nr*KP_ + c8) = *(uint4*)o;
}

// ---- LSTM [b][t][e] fp32 -> LT [b][e][t] bf16 (64x64 LDS transpose tiles) ----
__global__ __launch_bounds__(256) void k_ltrans(const float* __restrict__ LSTM,
                                                unsigned short* __restrict__ LT) {
  int e0 = blockIdx.x * 64, t0 = blockIdx.y * 64, b = blockIdx.z;
  __shared__ float tile[64][65];
  int tid = threadIdx.x;
  int tt = tid >> 2, c16 = (tid & 3) * 16;
  const float4* src = (const float4*)(LSTM + ((size_t)b*TE_ + t0 + tt)*EH_ + e0 + c16);
  float4 v0 = src[0], v1 = src[1], v2 = src[2], v3 = src[3];
  *(float4*)&tile[tt][c16]    = v0;
  *(float4*)&tile[tt][c16+4]  = v1;
  *(float4*)&tile[tt][c16+8]  = v2;
  *(float4*)&tile[tt][c16+12] = v3;
  __syncthreads();
  int e = tid >> 2, t16 = (tid & 3) * 16;
  unsigned short o[16];
  #pragma unroll
  for (int j = 0; j < 16; ++j) o[j] = f2bf(tile[t16+j][e]);
  unsigned short* dst = LT + ((size_t)b*EH_ + e0 + e)*TE_ + t0 + t16;
  *(uint4*)dst     = *(uint4*)&o[0];
  *(uint4*)(dst+8) = *(uint4*)&o[8];
}

// ---------- phase 1: banded logits as MFMA bf16 band-GEMM (reg-prefetched) ----------
#define BMM_M 64
#define LDA_  40
#define LDB_  40
__global__ __launch_bounds__(256) void k_bandmm(const float* __restrict__ LSTM,
                                                const float* __restrict__ phi,
                                                const float* __restrict__ Ua_w,
                                                const float* __restrict__ Ua_b,
                                                const float* __restrict__ va_w,
                                                const float* __restrict__ va_b,
                                                const float* __restrict__ wa,
                                                float* __restrict__ ET) {
  int t0 = blockIdx.x * BMM_M;   // 8 tiles
  int b  = blockIdx.y;           // 128
  int s_base = 321 - t0;
  __shared__ short sA[BMM_M * LDA_];
  __shared__ short sB[192 * LDB_];
  int tid = threadIdx.x;
  int wave = tid >> 6, lane = tid & 63;
  int quad = lane >> 4, l16 = lane & 15;

  f32x4 acc[4][3];
  #pragma unroll
  for (int m = 0; m < 4; ++m)
    #pragma unroll
    for (int n = 0; n < 3; ++n)
      acc[m][n] = (f32x4){0.f, 0.f, 0.f, 0.f};

  int arow = tid >> 2;             // 0..63
  int ach  = (tid & 3) * 8;        // shorts
  int aq   = ach >> 2;             // float4 units

  const float4* baseL = (const float4*)(LSTM + ((size_t)b*TE_ + t0 + arow)*EH_);
  const float4* baseP = (const float4*)(phi + (size_t)(t0 + arow)*EH_);
  const float4* baseU[3];
  int brow[3], bch[3];
  #pragma unroll
  for (int c = 0; c < 3; ++c) {
    int idx = c*256 + tid;
    brow[c] = idx >> 2;
    bch[c]  = (idx & 3) * 8;
    int s = s_base + brow[c];
    int sc = s < 0 ? 0 : (s > 511 ? 511 : s);
    baseU[c] = (const float4*)(Ua_w + (size_t)sc*EH_ + bch[c]);
  }

  float4 l0 = baseL[aq], l1 = baseL[aq+1], p0 = baseP[aq], p1 = baseP[aq+1];
  float4 u0[3], u1[3];
  #pragma unroll
  for (int c = 0; c < 3; ++c) { u0[c] = baseU[c][0]; u1[c] = baseU[c][1]; }

  for (int k0 = 0; k0 < EH_; k0 += 32) {
    unsigned short at[8];
    at[0]=f2bf(l0.x*p0.x); at[1]=f2bf(l0.y*p0.y); at[2]=f2bf(l0.z*p0.z); at[3]=f2bf(l0.w*p0.w);
    at[4]=f2bf(l1.x*p1.x); at[5]=f2bf(l1.y*p1.y); at[6]=f2bf(l1.z*p1.z); at[7]=f2bf(l1.w*p1.w);
    unsigned short bt[3][8];
    #pragma unroll
    for (int c = 0; c < 3; ++c) {
      bt[c][0]=f2bf(u0[c].x); bt[c][1]=f2bf(u0[c].y); bt[c][2]=f2bf(u0[c].z); bt[c][3]=f2bf(u0[c].w);
      bt[c][4]=f2bf(u1[c].x); bt[c][5]=f2bf(u1[c].y); bt[c][6]=f2bf(u1[c].z); bt[c][7]=f2bf(u1[c].w);
    }
    if (k0 + 32 < EH_) {                       // prefetch next chunk
      int q = (k0 + 32) >> 2;
      l0 = baseL[q+aq]; l1 = baseL[q+aq+1]; p0 = baseP[q+aq]; p1 = baseP[q+aq+1];
      #pragma unroll
      for (int c = 0; c < 3; ++c) { u0[c] = baseU[c][q]; u1[c] = baseU[c][q+1]; }
    }
    __syncthreads();
    *(uint4*)&sA[arow*LDA_ + ach] = *(uint4*)at;
    #pragma unroll
    for (int c = 0; c < 3; ++c)
      *(uint4*)&sB[brow[c]*LDB_ + bch[c]] = *(uint4*)bt[c];
    __syncthreads();
    bf16x8 bfr[3];
    #pragma unroll
    for (int n = 0; n < 3; ++n)
      bfr[n] = *(const bf16x8*)&sB[(l16 + (wave*3 + n)*16)*LDB_ + quad*8];
    #pragma unroll
    for (int m = 0; m < 4; ++m) {
      bf16x8 af = *(const bf16x8*)&sA[(l16 + m*16)*LDA_ + quad*8];
      #pragma unroll
      for (int n = 0; n < 3; ++n)
        acc[m][n] = __builtin_amdgcn_mfma_f32_16x16x32_bf16(af, bfr[n], acc[m][n], 0, 0, 0);
    }
  }

  float vb = va_b[0];
  #pragma unroll
  for (int n = 0; n < 3; ++n) {
    int s = s_base + wave*48 + n*16 + l16;
    #pragma unroll
    for (int m = 0; m < 4; ++m) {
      #pragma unroll
      for (int r = 0; r < 4; ++r) {
        int t = t0 + m*16 + quad*4 + r;
        int i = s + t - 384;
        if (i >= 0 && i < TD_) {
          float val;
          if (s >= 0) val = tanhf(acc[m][n][r] + Ua_b[s]) * va_w[TD_ + s] + vb;
          else        val = wa[b*TD_ + s + 128] + vb;
          ET[((size_t)b*TE_ + t)*TD_ + i] = val;
        }
      }
    }
  }
}

// ---------------- phase 2: softmax stats over t ----------------
__global__ __launch_bounds__(256) void k_stats(const float* __restrict__ ET,
                                               float* __restrict__ stat) {
  int i0 = blockIdx.x * 64, b = blockIdx.y;
  __shared__ float red[4][64], smax[64];
  int tid = threadIdx.x;
  int q = tid >> 6, il = tid & 63;
  const float* col = ET + (size_t)b*TE_*TD_ + i0 + il;
  float m = -1e30f;
  for (int t = q*128; t < q*128 + 128; ++t) m = fmaxf(m, col[(size_t)t*TD_]);
  red[q][il] = m;
  __syncthreads();
  if (tid < 64) {
    float mm = fmaxf(fmaxf(red[0][tid], red[1][tid]), fmaxf(red[2][tid], red[3][tid]));
    smax[tid] = mm;
  }
  __syncthreads();
  float mm = smax[il];
  float s = 0.f;
  for (int t = q*128; t < q*128 + 128; ++t) s += __expf(col[(size_t)t*TD_] - mm);
  __syncthreads();
  red[q][il] = s;
  __syncthreads();
  if (tid < 64) {
    float ss = red[0][tid] + red[1][tid] + red[2][tid] + red[3][tid];
    stat[b*TD_ + i0 + tid] = smax[tid];
    stat[(size_t)B_*TD_ + b*TD_ + i0 + tid] = 1.f/ss;
  }
}

// ---- ET [b][t][i] + stats -> P [b][i][t] bf16 (softmax applied, transposed) ----
__global__ __launch_bounds__(256) void k_trP(const float* __restrict__ ET,
                                             const float* __restrict__ stat,
                                             unsigned short* __restrict__ P) {
  int t0 = blockIdx.x * 64, i0 = blockIdx.y * 64, b = blockIdx.z;
  __shared__ float tile[64][65];
  __shared__ float smL[64], svL[64];
  int tid = threadIdx.x;
  if (tid < 64) {
    smL[tid] = stat[b*TD_ + i0 + tid];
    svL[tid] = stat[(size_t)B_*TD_ + b*TD_ + i0 + tid];
  }
  int tt = tid >> 2, c16 = (tid & 3) * 16;
  const float4* src = (const float4*)(ET + ((size_t)b*TE_ + t0 + tt)*TD_ + i0 + c16);
  float4 v[4]; v[0] = src[0]; v[1] = src[1]; v[2] = src[2]; v[3] = src[3];
  __syncthreads();
  const float* vf = (const float*)v;
  #pragma unroll
  for (int j = 0; j < 16; ++j)
    tile[tt][c16+j] = __expf(vf[j] - smL[c16+j]) * svL[c16+j];
  __syncthreads();
  int i = tid >> 2, t16 = (tid & 3) * 16;
  unsigned short o[16];
  #pragma unroll
  for (int j = 0; j < 16; ++j) o[j] = f2bf(tile[t16+j][i]);
  unsigned short* dst = P + ((size_t)b*TD_ + i0 + i)*TE_ + t0 + t16;
  *(uint4*)dst     = *(uint4*)&o[0];
  *(uint4*)(dst+8) = *(uint4*)&o[8];
}

// ---- fill X[:,512:640] from cp (bf16), zero pad ----
__global__ void k_cp_fill(const float* __restrict__ cp, unsigned short* __restrict__ X) {
  int id = blockIdx.x * 256 + threadIdx.x;  // 16384*16
  int m = id >> 4, c8 = (id & 15) * 8;
  int b = m >> 7;
  unsigned short o[8];
  #pragma unroll
  for (int j = 0; j < 8; ++j) {
    int c = c8 + j;
    o[j] = (c < CC_) ? f2bf(cp[b*CC_ + c]) : 0;
  }
  *(uint4*)(X + (size_t)m*KP_ + EH_ + c8) = *(uint4*)o;
}

// ------ phase 3 (MFMA): X[b*128+i][e] = sum_t P[b][i][t] * LT[b][e][t] ------
#define CI_LD 40
__global__ __launch_bounds__(256) void k_ci_mm(const unsigned short* __restrict__ P,
                                               const unsigned short* __restrict__ LT,
                                               unsigned short* __restrict__ X) {
  int b = blockIdx.x, e0 = blockIdx.y * 128;
  __shared__ short sA[128 * CI_LD];
  __shared__ short sB[128 * CI_LD];
  int tid = threadIdx.x;
  int wave = tid >> 6, lane = tid & 63, quad = lane >> 4, l16 = lane & 15;
  int wm = wave >> 1, wn = wave & 1;
  int row = tid >> 1, half = tid & 1, ho = half * 16;

  const unsigned short* pa = P + ((size_t)b*TD_ + row)*TE_ + ho;
  const unsigned short* pb = LT + ((size_t)b*EH_ + e0 + row)*TE_ + ho;

  f32x4 acc[4][4];
  #pragma unroll
  for (int m = 0; m < 4; ++m)
    #pragma unroll
    for (int n = 0; n < 4; ++n)
      acc[m][n] = (f32x4){0.f, 0.f, 0.f, 0.f};

  uint4 a0 = *(const uint4*)pa, a1 = *(const uint4*)(pa + 8);
  uint4 b0 = *(const uint4*)pb, b1 = *(const uint4*)(pb + 8);

  for (int k0 = 0; k0 < TE_; k0 += 32) {
    uint4 na0, na1, nb0, nb1;
    if (k0 + 32 < TE_) {
      na0 = *(const uint4*)(pa + k0 + 32); na1 = *(const uint4*)(pa + k0 + 40);
      nb0 = *(const uint4*)(pb + k0 + 32); nb1 = *(const uint4*)(pb + k0 + 40);
    }
    __syncthreads();
    *(uint4*)&sA[row*CI_LD + ho]     = a0;
    *(uint4*)&sA[row*CI_LD + ho + 8] = a1;
    *(uint4*)&sB[row*CI_LD + ho]     = b0;
    *(uint4*)&sB[row*CI_LD + ho + 8] = b1;
    __syncthreads();
    bf16x8 bfr[4];
    #pragma unroll
    for (int n = 0; n < 4; ++n)
      bfr[n] = *(const bf16x8*)&sB[(wn*64 + n*16 + l16)*CI_LD + quad*8];
    #pragma unroll
    for (int m = 0; m < 4; ++m) {
      bf16x8 af = *(const bf16x8*)&sA[(wm*64 + m*16 + l16)*CI_LD + quad*8];
      #pragma unroll
      for (int n = 0; n < 4; ++n)
        acc[m][n] = __builtin_amdgcn_mfma_f32_16x16x32_bf16(af, bfr[n], acc[m][n], 0, 0, 0);
    }
    a0 = na0; a1 = na1; b0 = nb0; b1 = nb1;
  }

  #pragma unroll
  for (int m = 0; m < 4; ++m) {
    int i = wm*64 + m*16 + quad*4;
    #pragma unroll
    for (int n = 0; n < 4; ++n) {
      int e = e0 + wn*64 + n*16 + l16;
      unsigned short* xp = X + ((size_t)b*TD_ + i)*KP_ + e;
      #pragma unroll
      for (int r = 0; r < 4; ++r)
        xp[(size_t)r*KP_] = f2bf(acc[m][n][r]);
    }
  }
}

// -- phase 4 (MFMA): gates = X @ Wr^T (rows dh*4+gate) + fused LSTM cell --
__global__ __launch_bounds__(256) void k_gates_mm(const unsigned short* __restrict__ Wr,
                                                  const unsigned short* __restrict__ X,
                                                  const float* __restrict__ hpre,
                                                  const float* __restrict__ m_i,
                                                  float* __restrict__ out) {
  int g0 = blockIdx.x * 128;    // 16 tiles over 2048 reordered gate-rows
  int mi0 = blockIdx.y * 128;   // 128 tiles over 16384 (b,i) rows
  __shared__ short sA[128 * CI_LD];
  __shared__ short sB[128 * CI_LD];
  int tid = threadIdx.x;
  int wave = tid >> 6, lane = tid & 63, quad = lane >> 4, l16 = lane & 15;
  int wg = wave >> 1, wmi = wave & 1;
  int row = tid >> 1, half = tid & 1, ho = half * 16;

  const unsigned short* pa = Wr + (size_t)(g0 + row)*KP_ + ho;
  const unsigned short* pb = X + (size_t)(mi0 + row)*KP_ + ho;

  f32x4 acc[4][4];
  #pragma unroll
  for (int m = 0; m < 4; ++m)
    #pragma unroll
    for (int n = 0; n < 4; ++n)
      acc[m][n] = (f32x4){0.f, 0.f, 0.f, 0.f};

  uint4 a0 = *(const uint4*)pa, a1 = *(const uint4*)(pa + 8);
  uint4 b0 = *(const uint4*)pb, b1 = *(const uint4*)(pb + 8);

  for (int k0 = 0; k0 < KP_; k0 += 32) {
    uint4 na0, na1, nb0, nb1;
    if (k0 + 32 < KP_) {
      na0 = *(const uint4*)(pa + k0 + 32); na1 = *(const uint4*)(pa + k0 + 40);
      nb0 = *(const uint4*)(pb + k0 + 32); nb1 = *(const uint4*)(pb + k0 + 40);
    }
    __syncthreads();
    *(uint4*)&sA[row*CI_LD + ho]     = a0;
    *(uint4*)&sA[row*CI_LD + ho + 8] = a1;
    *(uint4*)&sB[row*CI_LD + ho]     = b0;
    *(uint4*)&sB[row*CI_LD + ho + 8] = b1;
    __syncthreads();
    bf16x8 bfr[4];
    #pragma unroll
    for (int n = 0; n < 4; ++n)
      bfr[n] = *(const bf16x8*)&sB[(wmi*64 + n*16 + l16)*CI_LD + quad*8];
    #pragma unroll
    for (int m = 0; m < 4; ++m) {
      bf16x8 af = *(const bf16x8*)&sA[(wg*64 + m*16 + l16)*CI_LD + quad*8];
      #pragma unroll
      for (int n = 0; n < 4; ++n)
        acc[m][n] = __builtin_amdgcn_mfma_f32_16x16x32_bf16(af, bfr[n], acc[m][n], 0, 0, 0);
    }
    a0 = na0; a1 = na1; b0 = nb0; b1 = nb1;
  }

  // lane regs r=0..3 are exactly (ig,fg,gg,og) of dh = grow>>2
  #pragma unroll
  for (int m = 0; m < 4; ++m) {
    int dh = (g0 >> 2) + wg*16 + m*4 + quad;
    #pragma unroll
    for (int n = 0; n < 4; ++n) {
      int mi = mi0 + wmi*64 + n*16 + l16;
      int bb = mi >> 7;
      const float* hp = hpre + (size_t)bb*G_;
      float ig = acc[m][n][0] + hp[dh];
      float fg = acc[m][n][1] + hp[DH_ + dh];
      float gg = acc[m][n][2] + hp[2*DH_ + dh];
      float og = acc[m][n][3] + hp[3*DH_ + dh];
      float c  = sigm(fg)*m_i[(size_t)bb*DH_ + dh] + sigm(ig)*tanhf(gg);
      float h  = sigm(og)*tanhf(c);
      out[(size_t)mi*DH_ + dh] = h;
    }
  }
}

extern "C" void kernel_launch(void* const* d_in, const int* in_sizes, int n_in,
                              void* d_out, int out_size, void* d_ws, size_t ws_size,
                              hipStream_t stream) {
  (void)in_sizes; (void)n_in; (void)out_size; (void)ws_size;
  const float* LSTM  = (const float*)d_in[0];
  const float* CNNs  = (const float*)d_in[1];
  const float* Wa_w  = (const float*)d_in[2];
  const float* Wa_b  = (const float*)d_in[3];
  const float* Ua_w  = (const float*)d_in[4];
  const float* Ua_b  = (const float*)d_in[5];
  const float* va_w  = (const float*)d_in[6];
  const float* va_b  = (const float*)d_in[7];
  const float* phi_w = (const float*)d_in[8];
  const float* phi_b = (const float*)d_in[9];
  const float* Wih   = (const float*)d_in[10];
  const float* Whh   = (const float*)d_in[11];
  const float* bih   = (const float*)d_in[12];
  const float* bhh   = (const float*)d_in[13];
  const float* wij_w = (const float*)d_in[14];
  const float* wij_b = (const float*)d_in[15];
  const float* s_i   = (const float*)d_in[16];
  const float* m_i   = (const float*)d_in[17];
  float* out = (float*)d_out;
  char* ws = (char*)d_ws;

  float* phi  = (float*)(ws + OFF_PHI);
  float* wa   = (float*)(ws + OFF_WA);
  float* hpre = (float*)(ws + OFF_HPRE);
  float* ep   = (float*)(ws + OFF_EP);
  float* cp   = (float*)(ws + OFF_CP);
  float* stat = (float*)(ws + OFF_STAT);
  float* ET   = (float*)(ws + OFF_ET);
  unsigned short* X  = (unsigned short*)(ws + OFF_ET);   // aliases ET (dead after k_trP)
  unsigned short* P  = (unsigned short*)(ws + OFF_P);
  unsigned short* LT = (unsigned short*)(ws + OFF_LT);
  unsigned short* Wr = (unsigned short*)(ws + OFF_WR);

  k_phi     <<<dim3(2),        dim3(256),  0, stream>>>(phi_w, phi_b, phi);
  k_wa      <<<dim3(64),       dim3(256),  0, stream>>>(s_i, Wa_w, Wa_b, va_w, wa);
  k_hpre    <<<dim3(1024),     dim3(256),  0, stream>>>(s_i, Whh, bih, bhh, hpre);
  k_ep      <<<dim3(4),        dim3(256),  0, stream>>>(CNNs, wij_w, wij_b, s_i, ep);
  k_cnn_fin <<<dim3(1),        dim3(1024), 0, stream>>>(ep, CNNs, cp);
  k_cvtW    <<<dim3(640),      dim3(256),  0, stream>>>(Wih, Wr);
  k_ltrans  <<<dim3(8,8,128),  dim3(256),  0, stream>>>(LSTM, LT);
  k_bandmm  <<<dim3(8,128),    dim3(256),  0, stream>>>(LSTM, phi, Ua_w, Ua_b, va_w, va_b, wa, ET);
  k_stats   <<<dim3(2,128),    dim3(256),  0, stream>>>(ET, stat);
  k_trP     <<<dim3(8,2,128),  dim3(256),  0, stream>>>(ET, stat, P);
  k_cp_fill <<<dim3(1024),     dim3(256),  0, stream>>>(cp, X);
  k_ci_mm   <<<dim3(128,4),    dim3(256),  0, stream>>>(P, LT, X);
  k_gates_mm<<<dim3(16,128),   dim3(256),  0, stream>>>(Wr, X, hpre, m_i, out);
}